// Round 1
// baseline (510.180 us; speedup 1.0000x reference)
//
#include <hip/hip_runtime.h>
#include <math.h>

// DenseGATv2Layer: N=4096 nodes, IN=128, HEADS=4, OUT_DIM=64.
// out[i, h*64+d] = sum_j softmax_j( mask[i,j] ? lrelu(s_i[i,h]+s_j[j,h]) : -9e15 ) * hfeat[j,h,d]
//
// Pipeline (all on `stream`):
//   K0 detect_fmt : decide if adj_mask arrived as bool bytes or 4-byte elems (int32/float)
//   K1 pack_mask  : 67MB/16.7MB mask -> 2MB bitmask (read 3x later, format-agnostic)
//   K2 compute_h  : h = x@W (tiled, W cols coalesced), + s_src/s_dst via wave reduce.
//                   h stored TRANSPOSED per row: h_t[n*256 + d*4 + head] so the
//                   aggregation reads one float4 = all 4 heads at dim d (coalesced).
//   K3 gat_fused  : per block 16 dest rows; 2-pass (max, sumexp) per-lane over j then
//                   butterfly reduce; accumulate pass stages h chunks in LDS,
//                   p broadcast via LDS. Pure fp32.

#define N 4096
#define IN_DIM 128
#define HEADS 4
#define OUT_DIM 64
#define HD 256
#define NEG_INF -9.0e15f

// ws layout (bytes): needs ~6.13 MB total
#define WS_H_OFF    0u          // float h_t[N*HD]          (4 MB)
#define WS_SSRC_OFF 4194304u    // float s_src[N*HEADS]     (64 KB)
#define WS_SDST_OFF 4259840u    // float s_dst[N*HEADS]     (64 KB)
#define WS_BITS_OFF 4325376u    // uint  bits[N*128]        (2 MB)
#define WS_FLAG_OFF 6422528u    // int   flag

__device__ __forceinline__ float f4get(float4 v, int h) {
  return h == 0 ? v.x : h == 1 ? v.y : h == 2 ? v.z : v.w;
}
__device__ __forceinline__ float lrelu(float v) { return v > 0.f ? v : 0.2f * v; }

// ---------------- K0: mask format detection ----------------
// byte-bool data: every word has bytes in {0,1} ((w & 0xFEFEFEFE)==0) and, over
// 4096 words of bernoulli(0.1) data, some word > 1 with certainty.
// int32 0/1 data: words are exactly 0 or 1. float 0/1.0f data: 0x3F800000 trips
// the 0xFEFEFEFE test -> 4-byte path (nonzero test works for float too).
__global__ void detect_fmt(const unsigned* __restrict__ m, int* __restrict__ flag) {
  __shared__ int s_bad, s_gt1;
  if (threadIdx.x == 0) { s_bad = 0; s_gt1 = 0; }
  __syncthreads();
  int bad = 0, g = 0;
  for (int i = threadIdx.x; i < 4096; i += blockDim.x) {
    unsigned v = m[i];
    if (v & 0xFEFEFEFEu) bad = 1;
    if (v > 1u) g = 1;
  }
  if (bad) atomicOr(&s_bad, 1);
  if (g) atomicOr(&s_gt1, 1);
  __syncthreads();
  if (threadIdx.x == 0) *flag = (!s_bad && s_gt1) ? 1 : 0;  // 1 = byte elems
}

// ---------------- K1: pack mask to bits ----------------
__device__ __forceinline__ unsigned pack_bytes(unsigned v) {
  // 4 bytes (each 0/1) -> 4 bits
  return (v & 1u) | ((v >> 7) & 2u) | ((v >> 14) & 4u) | ((v >> 21) & 8u);
}

__global__ __launch_bounds__(256) void pack_mask_k(const void* __restrict__ mraw,
                                                   unsigned* __restrict__ bits,
                                                   const int* __restrict__ flag) {
  int w = blockIdx.x * blockDim.x + threadIdx.x;  // word index, N*N/32 = 524288 total
  unsigned ob = 0u;
  if (*flag) {
    const uint4* p = (const uint4*)((const unsigned char*)mraw + (size_t)w * 32u);
    uint4 a = p[0], b = p[1];
    ob  =  pack_bytes(a.x)        | (pack_bytes(a.y) << 4)  | (pack_bytes(a.z) << 8)  | (pack_bytes(a.w) << 12);
    ob |= (pack_bytes(b.x) << 16) | (pack_bytes(b.y) << 20) | (pack_bytes(b.z) << 24) | (pack_bytes(b.w) << 28);
  } else {
    const uint4* p = (const uint4*)((const unsigned*)mraw + (size_t)w * 32u);
#pragma unroll
    for (int k = 0; k < 8; ++k) {
      uint4 v = p[k];
      ob |= (v.x ? 1u : 0u) << (4 * k);
      ob |= (v.y ? 1u : 0u) << (4 * k + 1);
      ob |= (v.z ? 1u : 0u) << (4 * k + 2);
      ob |= (v.w ? 1u : 0u) << (4 * k + 3);
    }
  }
  bits[w] = ob;
}

// ---------------- K2: h = x@W, s_src/s_dst ----------------
// 256 blocks x 256 threads; block handles 16 rows, thread c = output column.
// Wave w == head w (c>>6), lane == dim d (c&63): s reductions are wave reduces.
__global__ __launch_bounds__(256) void compute_h(const float* __restrict__ x,
                                                 const float* __restrict__ W,
                                                 const float* __restrict__ a_src,
                                                 const float* __restrict__ a_dst,
                                                 float* __restrict__ h_t,
                                                 float* __restrict__ s_src,
                                                 float* __restrict__ s_dst) {
  __shared__ float xs[16][IN_DIM];  // 8 KB
  const int i0 = blockIdx.x * 16;
  const int c = threadIdx.x;
  for (int idx = c; idx < 16 * IN_DIM; idx += 256) {
    xs[idx >> 7][idx & 127] = x[(size_t)(i0 + (idx >> 7)) * IN_DIM + (idx & 127)];
  }
  __syncthreads();

  float acc[16];
#pragma unroll
  for (int r = 0; r < 16; ++r) acc[r] = 0.f;

  for (int k = 0; k < IN_DIM; ++k) {
    float wv = W[(size_t)k * HD + c];  // coalesced: 256 consecutive floats
#pragma unroll
    for (int r = 0; r < 16; ++r) acc[r] = fmaf(xs[r][k], wv, acc[r]);
  }

  const int hw = c >> 6, lane = c & 63;
  // transposed store: h_t[n*256 + d*4 + head]
#pragma unroll
  for (int r = 0; r < 16; ++r)
    h_t[(size_t)(i0 + r) * HD + lane * 4 + hw] = acc[r];

  const float as = a_src[lane], ad = a_dst[lane];
#pragma unroll
  for (int r = 0; r < 16; ++r) {
    float vs = acc[r] * as, vd = acc[r] * ad;
#pragma unroll
    for (int off = 1; off < 64; off <<= 1) {
      vs += __shfl_xor(vs, off);
      vd += __shfl_xor(vd, off);
    }
    if (lane == 0) {
      s_src[(size_t)(i0 + r) * HEADS + hw] = vs;
      s_dst[(size_t)(i0 + r) * HEADS + hw] = vd;
    }
  }
}

// ---------------- K3: fused masked-softmax + aggregation ----------------
// 256 blocks x 256 threads (4 waves). Block = 16 dest rows, wave = 4 rows.
__global__ __launch_bounds__(256) void gat_fused(const float* __restrict__ h_t,
                                                 const float* __restrict__ s_src,
                                                 const float* __restrict__ s_dst,
                                                 const unsigned* __restrict__ bits,
                                                 float* __restrict__ out) {
  __shared__ float hbuf[32 * HD];    // 32 KB: 32 j-rows of h_t
  __shared__ float4 pbuf[4][4][32];  // [wave][local row][jj] -> 4 heads; 8 KB

  const int tid = threadIdx.x;
  const int wave = tid >> 6;
  const int lane = tid & 63;
  const int r0 = blockIdx.x * 16 + wave * 4;

  const float4* sd4 = (const float4*)s_dst;
  const unsigned long long* mb64 = (const unsigned long long*)bits;

  float si[4][4];
#pragma unroll
  for (int r = 0; r < 4; ++r) {
    float4 t = ((const float4*)s_src)[r0 + r];
#pragma unroll
    for (int h = 0; h < 4; ++h) si[r][h] = f4get(t, h);
  }

  float m[4][4], l[4][4];
#pragma unroll
  for (int r = 0; r < 4; ++r)
#pragma unroll
    for (int h = 0; h < 4; ++h) { m[r][h] = NEG_INF; l[r][h] = 0.f; }

  // ---- phase 1a: per-lane running max over j (j = jb*64 + lane) ----
  for (int jb = 0; jb < N / 64; ++jb) {
    float4 sjv = sd4[jb * 64 + lane];
#pragma unroll
    for (int r = 0; r < 4; ++r) {
      unsigned long long w = mb64[(size_t)(r0 + r) * 64 + jb];
      bool e = (w >> lane) & 1ull;
#pragma unroll
      for (int h = 0; h < 4; ++h) {
        float v = lrelu(si[r][h] + f4get(sjv, h));
        m[r][h] = fmaxf(m[r][h], e ? v : NEG_INF);
      }
    }
  }
#pragma unroll
  for (int off = 1; off < 64; off <<= 1)
#pragma unroll
    for (int r = 0; r < 4; ++r)
#pragma unroll
      for (int h = 0; h < 4; ++h)
        m[r][h] = fmaxf(m[r][h], __shfl_xor(m[r][h], off));

  // ---- phase 1b: per-lane sum of exp(e - m) ----
  for (int jb = 0; jb < N / 64; ++jb) {
    float4 sjv = sd4[jb * 64 + lane];
#pragma unroll
    for (int r = 0; r < 4; ++r) {
      unsigned long long w = mb64[(size_t)(r0 + r) * 64 + jb];
      bool e = (w >> lane) & 1ull;
#pragma unroll
      for (int h = 0; h < 4; ++h) {
        float v = lrelu(si[r][h] + f4get(sjv, h));
        l[r][h] += __expf((e ? v : NEG_INF) - m[r][h]);
      }
    }
  }
#pragma unroll
  for (int off = 1; off < 64; off <<= 1)
#pragma unroll
    for (int r = 0; r < 4; ++r)
#pragma unroll
      for (int h = 0; h < 4; ++h)
        l[r][h] += __shfl_xor(l[r][h], off);

  float il[4][4];
#pragma unroll
  for (int r = 0; r < 4; ++r)
#pragma unroll
    for (int h = 0; h < 4; ++h) il[r][h] = 1.f / l[r][h];  // l >= 1 always

  // ---- phase 2: accumulate out = p . h ----
  // lanes 0..31 compute p for local rows {0,1}, lanes 32..63 for rows {2,3}
  const bool hi = lane >= 32;
  const int jlane = lane & 31;
  float msA[4], msB[4], ilA[4], ilB[4], siA[4], siB[4];
#pragma unroll
  for (int h = 0; h < 4; ++h) {
    msA[h] = hi ? m[2][h] : m[0][h];
    msB[h] = hi ? m[3][h] : m[1][h];
    ilA[h] = hi ? il[2][h] : il[0][h];
    ilB[h] = hi ? il[3][h] : il[1][h];
    siA[h] = hi ? si[2][h] : si[0][h];
    siB[h] = hi ? si[3][h] : si[1][h];
  }
  const unsigned* mrowA = bits + (size_t)(r0 + (hi ? 2 : 0)) * 128;
  const unsigned* mrowB = mrowA + 128;

  float acc[4][4];
#pragma unroll
  for (int r = 0; r < 4; ++r)
#pragma unroll
    for (int h = 0; h < 4; ++h) acc[r][h] = 0.f;

  for (int jb = 0; jb < N / 32; ++jb) {
    // stage 32 j-rows of h_t (8192 floats = 2048 float4, 8 per thread)
    const float4* src4 = (const float4*)(h_t + (size_t)jb * 32 * HD);
    float4* dst4 = (float4*)hbuf;
#pragma unroll
    for (int k = 0; k < 8; ++k) dst4[tid + 256 * k] = src4[tid + 256 * k];

    // p for this chunk (j = jb*32 + jlane), two local rows per lane
    float4 sjv = sd4[jb * 32 + jlane];
    unsigned wA = mrowA[jb], wB = mrowB[jb];
    bool eA = (wA >> jlane) & 1u, eB = (wB >> jlane) & 1u;
    float pA[4], pB[4];
#pragma unroll
    for (int h = 0; h < 4; ++h) {
      float vA = lrelu(siA[h] + f4get(sjv, h));
      float vB = lrelu(siB[h] + f4get(sjv, h));
      pA[h] = __expf((eA ? vA : NEG_INF) - msA[h]) * ilA[h];
      pB[h] = __expf((eB ? vB : NEG_INF) - msB[h]) * ilB[h];
    }
    pbuf[wave][hi ? 2 : 0][jlane] = make_float4(pA[0], pA[1], pA[2], pA[3]);
    pbuf[wave][hi ? 3 : 1][jlane] = make_float4(pB[0], pB[1], pB[2], pB[3]);
    __syncthreads();

    // accumulate: lane = dim d; hv = all 4 heads at dim d for row j
#pragma unroll 4
    for (int jj = 0; jj < 32; ++jj) {
      float4 hv = ((const float4*)hbuf)[jj * 64 + lane];
      float4 p0 = pbuf[wave][0][jj];
      float4 p1 = pbuf[wave][1][jj];
      float4 p2 = pbuf[wave][2][jj];
      float4 p3 = pbuf[wave][3][jj];
      acc[0][0] = fmaf(p0.x, hv.x, acc[0][0]); acc[0][1] = fmaf(p0.y, hv.y, acc[0][1]);
      acc[0][2] = fmaf(p0.z, hv.z, acc[0][2]); acc[0][3] = fmaf(p0.w, hv.w, acc[0][3]);
      acc[1][0] = fmaf(p1.x, hv.x, acc[1][0]); acc[1][1] = fmaf(p1.y, hv.y, acc[1][1]);
      acc[1][2] = fmaf(p1.z, hv.z, acc[1][2]); acc[1][3] = fmaf(p1.w, hv.w, acc[1][3]);
      acc[2][0] = fmaf(p2.x, hv.x, acc[2][0]); acc[2][1] = fmaf(p2.y, hv.y, acc[2][1]);
      acc[2][2] = fmaf(p2.z, hv.z, acc[2][2]); acc[2][3] = fmaf(p2.w, hv.w, acc[2][3]);
      acc[3][0] = fmaf(p3.x, hv.x, acc[3][0]); acc[3][1] = fmaf(p3.y, hv.y, acc[3][1]);
      acc[3][2] = fmaf(p3.z, hv.z, acc[3][2]); acc[3][3] = fmaf(p3.w, hv.w, acc[3][3]);
    }
    __syncthreads();
  }

  // epilogue: out[i, h*64 + d], d = lane (coalesced)
#pragma unroll
  for (int r = 0; r < 4; ++r)
#pragma unroll
    for (int h = 0; h < 4; ++h)
      out[(size_t)(r0 + r) * HD + h * 64 + lane] = acc[r][h];
}

extern "C" void kernel_launch(void* const* d_in, const int* in_sizes, int n_in,
                              void* d_out, int out_size, void* d_ws, size_t ws_size,
                              hipStream_t stream) {
  (void)in_sizes; (void)n_in; (void)out_size; (void)ws_size;
  const float* x = (const float*)d_in[0];
  const void* mask = d_in[1];
  const float* W = (const float*)d_in[2];
  const float* a_src = (const float*)d_in[3];
  const float* a_dst = (const float*)d_in[4];
  float* out = (float*)d_out;

  char* ws = (char*)d_ws;
  float* h_t = (float*)(ws + WS_H_OFF);
  float* s_src = (float*)(ws + WS_SSRC_OFF);
  float* s_dst = (float*)(ws + WS_SDST_OFF);
  unsigned* bits = (unsigned*)(ws + WS_BITS_OFF);
  int* flag = (int*)(ws + WS_FLAG_OFF);

  detect_fmt<<<1, 1024, 0, stream>>>((const unsigned*)mask, flag);
  pack_mask_k<<<(N * N / 32) / 256, 256, 0, stream>>>(mask, bits, flag);
  compute_h<<<N / 16, 256, 0, stream>>>(x, W, a_src, a_dst, h_t, s_src, s_dst);
  gat_fused<<<N / 16, 256, 0, stream>>>(h_t, s_src, s_dst, bits, out);
}

// Round 2
// 254.640 us; speedup vs baseline: 2.0035x; 2.0035x over previous
//
#include <hip/hip_runtime.h>
#include <math.h>

// DenseGATv2Layer: N=4096, IN=128, HEADS=4, OUT_DIM=64.
// R1: MFMA aggregation. R0 post-mortem showed gat_fused was DS-pipe bound
// (5 ds_read_b128 per 16 FMAs on the shared per-CU LDS unit = 410 us).
// New pipeline:
//   K0 detect_fmt : mask byte-vs-word format probe
//   K1 pack_mask  : mask -> 2MB bitmask
//   K2 compute_h  : h = x@W; writes h_c16 fp16 TRANSPOSED [h*64+d][j] (2MB, L2-resident),
//                   s_src/s_dst [i][4], s_dst_t [h][j]
//   K3 gat_scores : per-row m[i,h], il[i,h]=1/l (2-pass, bitmask, butterfly reduce)
//   K4 gat_aggr   : MFMA 16x16x32 f16. A-frag (P) synthesized IN REGISTERS per lane
//                   (rank-1 scores: p = exp(lrelu(si+sj)-m)*il) -> no LDS at all.
//                   B-frag loaded straight from h_c16. wave=head, block=16 rows,
//                   grid = 256 i-tiles x 4 j-quarters, atomicAdd partials into out.

#define N 4096
#define IN_DIM 128
#define HEADS 4
#define OUT_DIM 64
#define HD 256
#define NEG_INF -9.0e15f

typedef _Float16 f16x8 __attribute__((ext_vector_type(8)));
typedef float f32x4 __attribute__((ext_vector_type(4)));

// ws layout (bytes), total ~4.3 MB
#define WS_HC_OFF   0u          // _Float16 h_c16[256][4096]  (2 MB)
#define WS_SSRC_OFF 2097152u    // float s_src[N][4]          (64 KB)
#define WS_SDST_OFF 2162688u    // float s_dst[N][4]          (64 KB)
#define WS_SDT_OFF  2228224u    // float s_dst_t[4][N]        (64 KB)
#define WS_M_OFF    2293760u    // float m_ws[N][4]           (64 KB)
#define WS_IL_OFF   2359296u    // float il_ws[N][4]          (64 KB)
#define WS_BITS_OFF 2424832u    // uint  bits[N][128]         (2 MB)
#define WS_FLAG_OFF 4521984u    // int   flag

__device__ __forceinline__ float f4get(float4 v, int h) {
  return h == 0 ? v.x : h == 1 ? v.y : h == 2 ? v.z : v.w;
}
__device__ __forceinline__ float lrelu(float v) { return fmaxf(v, 0.2f * v); }

// ---------------- K0: mask format detection ----------------
__global__ void detect_fmt(const unsigned* __restrict__ m, int* __restrict__ flag) {
  __shared__ int s_bad, s_gt1;
  if (threadIdx.x == 0) { s_bad = 0; s_gt1 = 0; }
  __syncthreads();
  int bad = 0, g = 0;
  for (int i = threadIdx.x; i < 4096; i += blockDim.x) {
    unsigned v = m[i];
    if (v & 0xFEFEFEFEu) bad = 1;
    if (v > 1u) g = 1;
  }
  if (bad) atomicOr(&s_bad, 1);
  if (g) atomicOr(&s_gt1, 1);
  __syncthreads();
  if (threadIdx.x == 0) *flag = (!s_bad && s_gt1) ? 1 : 0;  // 1 = byte elems
}

// ---------------- K1: pack mask to bits ----------------
__device__ __forceinline__ unsigned pack_bytes(unsigned v) {
  return (v & 1u) | ((v >> 7) & 2u) | ((v >> 14) & 4u) | ((v >> 21) & 8u);
}

__global__ __launch_bounds__(256) void pack_mask_k(const void* __restrict__ mraw,
                                                   unsigned* __restrict__ bits,
                                                   const int* __restrict__ flag) {
  int w = blockIdx.x * blockDim.x + threadIdx.x;
  unsigned ob = 0u;
  if (*flag) {
    const uint4* p = (const uint4*)((const unsigned char*)mraw + (size_t)w * 32u);
    uint4 a = p[0], b = p[1];
    ob  =  pack_bytes(a.x)        | (pack_bytes(a.y) << 4)  | (pack_bytes(a.z) << 8)  | (pack_bytes(a.w) << 12);
    ob |= (pack_bytes(b.x) << 16) | (pack_bytes(b.y) << 20) | (pack_bytes(b.z) << 24) | (pack_bytes(b.w) << 28);
  } else {
    const uint4* p = (const uint4*)((const unsigned*)mraw + (size_t)w * 32u);
#pragma unroll
    for (int k = 0; k < 8; ++k) {
      uint4 v = p[k];
      ob |= (v.x ? 1u : 0u) << (4 * k);
      ob |= (v.y ? 1u : 0u) << (4 * k + 1);
      ob |= (v.z ? 1u : 0u) << (4 * k + 2);
      ob |= (v.w ? 1u : 0u) << (4 * k + 3);
    }
  }
  bits[w] = ob;
}

// ---------------- K2: h = x@W; h_c16 (fp16 transposed), s_src/s_dst/s_dst_t ----------------
__global__ __launch_bounds__(256) void compute_h(const float* __restrict__ x,
                                                 const float* __restrict__ W,
                                                 const float* __restrict__ a_src,
                                                 const float* __restrict__ a_dst,
                                                 _Float16* __restrict__ h_c16,
                                                 float* __restrict__ s_src,
                                                 float* __restrict__ s_dst,
                                                 float* __restrict__ s_dst_t) {
  __shared__ float xs[16][IN_DIM];  // 8 KB
  const int i0 = blockIdx.x * 16;
  const int c = threadIdx.x;  // c = head*64 + d == row index of h_c16
  for (int idx = c; idx < 16 * IN_DIM; idx += 256) {
    xs[idx >> 7][idx & 127] = x[(size_t)(i0 + (idx >> 7)) * IN_DIM + (idx & 127)];
  }
  __syncthreads();

  float acc[16];
#pragma unroll
  for (int r = 0; r < 16; ++r) acc[r] = 0.f;

  for (int k = 0; k < IN_DIM; ++k) {
    float wv = W[(size_t)k * HD + c];  // coalesced
#pragma unroll
    for (int r = 0; r < 16; ++r) acc[r] = fmaf(xs[r][k], wv, acc[r]);
  }

  // fp16 transposed store: h_c16[c][i0..i0+15]
  f16x8 lo, hi;
#pragma unroll
  for (int r = 0; r < 8; ++r) { lo[r] = (_Float16)acc[r]; hi[r] = (_Float16)acc[r + 8]; }
  *(f16x8*)(h_c16 + (size_t)c * N + i0) = lo;
  *(f16x8*)(h_c16 + (size_t)c * N + i0 + 8) = hi;

  const int hw = c >> 6, lane = c & 63;
  const float as = a_src[lane], ad = a_dst[lane];
#pragma unroll
  for (int r = 0; r < 16; ++r) {
    float vs = acc[r] * as, vd = acc[r] * ad;
#pragma unroll
    for (int off = 1; off < 64; off <<= 1) {
      vs += __shfl_xor(vs, off);
      vd += __shfl_xor(vd, off);
    }
    if (lane == 0) {
      s_src[(size_t)(i0 + r) * HEADS + hw] = vs;
      s_dst[(size_t)(i0 + r) * HEADS + hw] = vd;
      s_dst_t[(size_t)hw * N + (i0 + r)] = vd;
    }
  }
}

// ---------------- K3: per-row softmax stats (m, 1/l) ----------------
// 512 blocks x 256 thr; block = 8 rows, wave = 2 rows, lane = j chunk of 64.
__global__ __launch_bounds__(256) void gat_scores(const float* __restrict__ s_src,
                                                  const float* __restrict__ s_dst,
                                                  const unsigned* __restrict__ bits,
                                                  float* __restrict__ m_ws,
                                                  float* __restrict__ il_ws) {
  const int tid = threadIdx.x;
  const int wave = tid >> 6;
  const int lane = tid & 63;
  const int r0 = blockIdx.x * 8 + wave * 2;

  const float4* sd4 = (const float4*)s_dst;
  const unsigned long long* mb64 = (const unsigned long long*)bits;

  float si[2][4];
#pragma unroll
  for (int r = 0; r < 2; ++r) {
    float4 t = ((const float4*)s_src)[r0 + r];
#pragma unroll
    for (int h = 0; h < 4; ++h) si[r][h] = f4get(t, h);
  }

  float m[2][4], l[2][4];
#pragma unroll
  for (int r = 0; r < 2; ++r)
#pragma unroll
    for (int h = 0; h < 4; ++h) { m[r][h] = NEG_INF; l[r][h] = 0.f; }

  for (int jb = 0; jb < N / 64; ++jb) {
    float4 sjv = sd4[jb * 64 + lane];
#pragma unroll
    for (int r = 0; r < 2; ++r) {
      unsigned long long w = mb64[(size_t)(r0 + r) * 64 + jb];
      bool e = (w >> lane) & 1ull;
#pragma unroll
      for (int h = 0; h < 4; ++h) {
        float v = lrelu(si[r][h] + f4get(sjv, h));
        m[r][h] = fmaxf(m[r][h], e ? v : NEG_INF);
      }
    }
  }
#pragma unroll
  for (int off = 1; off < 64; off <<= 1)
#pragma unroll
    for (int r = 0; r < 2; ++r)
#pragma unroll
      for (int h = 0; h < 4; ++h)
        m[r][h] = fmaxf(m[r][h], __shfl_xor(m[r][h], off));

  for (int jb = 0; jb < N / 64; ++jb) {
    float4 sjv = sd4[jb * 64 + lane];
#pragma unroll
    for (int r = 0; r < 2; ++r) {
      unsigned long long w = mb64[(size_t)(r0 + r) * 64 + jb];
      bool e = (w >> lane) & 1ull;
#pragma unroll
      for (int h = 0; h < 4; ++h) {
        float v = lrelu(si[r][h] + f4get(sjv, h));
        l[r][h] += __expf((e ? v : NEG_INF) - m[r][h]);
      }
    }
  }
#pragma unroll
  for (int off = 1; off < 64; off <<= 1)
#pragma unroll
    for (int r = 0; r < 2; ++r)
#pragma unroll
      for (int h = 0; h < 4; ++h)
        l[r][h] += __shfl_xor(l[r][h], off);

  if (lane == 0) {
#pragma unroll
    for (int r = 0; r < 2; ++r)
#pragma unroll
      for (int h = 0; h < 4; ++h) {
        m_ws[(size_t)(r0 + r) * HEADS + h] = m[r][h];
        il_ws[(size_t)(r0 + r) * HEADS + h] = 1.f / l[r][h];
      }
  }
}

// ---------------- K4: MFMA aggregation ----------------
// 1024 blocks x 256 thr. block = (itile = bid>>2 -> 16 rows) x (jq = bid&3 -> 1024 j's).
// wave = head. Per 32-j chunk: A-frag (P) synthesized in regs, 4 B-frags from h_c16,
// 4 mfma_f32_16x16x32_f16 (ntiles over d). Epilogue: atomicAdd partials.
__global__ __launch_bounds__(256) void gat_aggr(const _Float16* __restrict__ h_c16,
                                                const float* __restrict__ s_src,
                                                const float* __restrict__ s_dst_t,
                                                const float* __restrict__ m_ws,
                                                const float* __restrict__ il_ws,
                                                const unsigned* __restrict__ bits,
                                                float* __restrict__ out) {
  const int tid = threadIdx.x;
  const int head = tid >> 6;       // wave = head
  const int lane = tid & 63;
  const int m15 = lane & 15;       // A: M-row / B: N-col / D: col
  const int quad = lane >> 4;      // k = quad*8 + t
  const int itile = blockIdx.x >> 2;
  const int jq = blockIdx.x & 3;
  const int i0 = itile * 16;
  const int row = i0 + m15;

  const float si = s_src[(size_t)row * HEADS + head];
  const float mr = m_ws[(size_t)row * HEADS + head];
  const float ilr = il_ws[(size_t)row * HEADS + head];

  const unsigned* mrow = bits + (size_t)row * 128 + jq * 32;          // 32 words = 1024 j
  const float* sjb = s_dst_t + (size_t)head * N + jq * 1024 + quad * 8;
  const _Float16* hrow = h_c16 + ((size_t)(head * 64 + m15)) * N + jq * 1024 + quad * 8;

  f32x4 acc0 = {0.f, 0.f, 0.f, 0.f}, acc1 = acc0, acc2 = acc0, acc3 = acc0;

  for (int c = 0; c < 32; ++c) {
    const int j0 = c * 32;
    const unsigned w = mrow[c];
    const float4 sa = *(const float4*)(sjb + j0);
    const float4 sb = *(const float4*)(sjb + j0 + 4);
    const float sjs[8] = {sa.x, sa.y, sa.z, sa.w, sb.x, sb.y, sb.z, sb.w};

    f16x8 afrag;
#pragma unroll
    for (int t = 0; t < 8; ++t) {
      float v = lrelu(si + sjs[t]);
      float e = ((w >> (quad * 8 + t)) & 1u) ? v : NEG_INF;
      afrag[t] = (_Float16)(__expf(e - mr) * ilr);
    }

    const f16x8 b0 = *(const f16x8*)(hrow + j0);
    const f16x8 b1 = *(const f16x8*)(hrow + (size_t)16 * N + j0);
    const f16x8 b2 = *(const f16x8*)(hrow + (size_t)32 * N + j0);
    const f16x8 b3 = *(const f16x8*)(hrow + (size_t)48 * N + j0);

    acc0 = __builtin_amdgcn_mfma_f32_16x16x32_f16(afrag, b0, acc0, 0, 0, 0);
    acc1 = __builtin_amdgcn_mfma_f32_16x16x32_f16(afrag, b1, acc1, 0, 0, 0);
    acc2 = __builtin_amdgcn_mfma_f32_16x16x32_f16(afrag, b2, acc2, 0, 0, 0);
    acc3 = __builtin_amdgcn_mfma_f32_16x16x32_f16(afrag, b3, acc3, 0, 0, 0);
  }

  // D layout: col = lane&15 (d within ntile), row = quad*4 + reg (i within tile)
  float* obase = out + (size_t)(i0 + quad * 4) * HD + head * 64 + m15;
#pragma unroll
  for (int reg = 0; reg < 4; ++reg) {
    atomicAdd(obase + (size_t)reg * HD + 0,  acc0[reg]);
    atomicAdd(obase + (size_t)reg * HD + 16, acc1[reg]);
    atomicAdd(obase + (size_t)reg * HD + 32, acc2[reg]);
    atomicAdd(obase + (size_t)reg * HD + 48, acc3[reg]);
  }
}

extern "C" void kernel_launch(void* const* d_in, const int* in_sizes, int n_in,
                              void* d_out, int out_size, void* d_ws, size_t ws_size,
                              hipStream_t stream) {
  (void)in_sizes; (void)n_in; (void)ws_size;
  const float* x = (const float*)d_in[0];
  const void* mask = d_in[1];
  const float* W = (const float*)d_in[2];
  const float* a_src = (const float*)d_in[3];
  const float* a_dst = (const float*)d_in[4];
  float* out = (float*)d_out;

  char* ws = (char*)d_ws;
  _Float16* h_c16 = (_Float16*)(ws + WS_HC_OFF);
  float* s_src = (float*)(ws + WS_SSRC_OFF);
  float* s_dst = (float*)(ws + WS_SDST_OFF);
  float* s_dst_t = (float*)(ws + WS_SDT_OFF);
  float* m_ws = (float*)(ws + WS_M_OFF);
  float* il_ws = (float*)(ws + WS_IL_OFF);
  unsigned* bits = (unsigned*)(ws + WS_BITS_OFF);
  int* flag = (int*)(ws + WS_FLAG_OFF);

  detect_fmt<<<1, 1024, 0, stream>>>((const unsigned*)mask, flag);
  pack_mask_k<<<(N * N / 32) / 256, 256, 0, stream>>>(mask, bits, flag);
  compute_h<<<N / 16, 256, 0, stream>>>(x, W, a_src, a_dst, h_c16, s_src, s_dst, s_dst_t);
  gat_scores<<<N / 8, 256, 0, stream>>>(s_src, s_dst, bits, m_ws, il_ws);
  hipMemsetAsync(out, 0, (size_t)out_size * sizeof(float), stream);
  gat_aggr<<<(N / 16) * 4, 256, 0, stream>>>(h_c16, s_src, s_dst_t, m_ws, il_ws, bits, out);
}

// Round 3
// 226.813 us; speedup vs baseline: 2.2493x; 1.1227x over previous
//
#include <hip/hip_runtime.h>
#include <math.h>

// DenseGATv2Layer: N=4096, IN=128, HEADS=4, OUT_DIM=64.
// R2: (1) atomic-free aggregation via disjoint partial slices + reduce kernel
//     (R1's gat_aggr showed MfmaUtil 3.8 / VALUBusy 30 -> retire-bound on 4.2M
//      fp32 atomicAdds ~ 70us); (2) single-pass softmax stats, no max-subtract
//     (scores are O(+-10); empty rows -> exact uniform via (U=0, log2l=12));
//     (3) compute_h reads x at block-uniform addresses (s_load broadcast) --
//     kills the ds_read_b32 broadcast bottleneck (~20us).
// Pipeline: detect_fmt -> pack_mask (2MB bitmask) -> compute_h (h fp16
// transposed [hd][j] + s_src/s_dst/s_dst_t) -> gat_scores (l only, 1 pass) ->
// gat_aggr (MFMA 16x16x32 f16, A-frag synthesized in registers, partial
// stores) -> reduce_part.

#define N 4096
#define IN_DIM 128
#define HEADS 4
#define OUT_DIM 64
#define HD 256
#define NEG_INF -9.0e15f
#define LOG2E 1.4426950408889634f

typedef _Float16 f16x8 __attribute__((ext_vector_type(8)));
typedef float f32x4 __attribute__((ext_vector_type(4)));

// ws layout (bytes)
#define WS_HC_OFF    0u          // _Float16 h_c16[256][4096]   (2 MB)
#define WS_SSRC_OFF  2097152u    // float s_src[N][4]           (64 KB)
#define WS_SDST_OFF  2162688u    // float s_dst[N][4]           (64 KB)
#define WS_SDT_OFF   2228224u    // float s_dst_t[4][N]         (64 KB)
#define WS_L2L_OFF   2293760u    // float log2l[N][4]           (64 KB)
#define WS_U_OFF     2359296u    // float U[N][4]               (64 KB)
#define WS_BITS_OFF  2424832u    // uint bits[N][128]           (2 MB)
#define WS_FLAG_OFF  4521984u    // int flag
#define WS_PART_OFF  4718592u    // float partial[4][N][256]    (16 MB)
#define WS_NEEDED    (4718592u + 16777216u)

__device__ __forceinline__ float f4get(float4 v, int h) {
  return h == 0 ? v.x : h == 1 ? v.y : h == 2 ? v.z : v.w;
}
__device__ __forceinline__ float lrelu(float v) { return fmaxf(v, 0.2f * v); }

// ---------------- K0: mask format detection ----------------
__global__ void detect_fmt(const unsigned* __restrict__ m, int* __restrict__ flag) {
  __shared__ int s_bad, s_gt1;
  if (threadIdx.x == 0) { s_bad = 0; s_gt1 = 0; }
  __syncthreads();
  int bad = 0, g = 0;
  for (int i = threadIdx.x; i < 4096; i += blockDim.x) {
    unsigned v = m[i];
    if (v & 0xFEFEFEFEu) bad = 1;
    if (v > 1u) g = 1;
  }
  if (bad) atomicOr(&s_bad, 1);
  if (g) atomicOr(&s_gt1, 1);
  __syncthreads();
  if (threadIdx.x == 0) *flag = (!s_bad && s_gt1) ? 1 : 0;  // 1 = byte elems
}

// ---------------- K1: pack mask to bits ----------------
__device__ __forceinline__ unsigned pack_bytes(unsigned v) {
  return (v & 1u) | ((v >> 7) & 2u) | ((v >> 14) & 4u) | ((v >> 21) & 8u);
}

__global__ __launch_bounds__(256) void pack_mask_k(const void* __restrict__ mraw,
                                                   unsigned* __restrict__ bits,
                                                   const int* __restrict__ flag) {
  int w = blockIdx.x * blockDim.x + threadIdx.x;
  unsigned ob = 0u;
  if (*flag) {
    const uint4* p = (const uint4*)((const unsigned char*)mraw + (size_t)w * 32u);
    uint4 a = p[0], b = p[1];
    ob  =  pack_bytes(a.x)        | (pack_bytes(a.y) << 4)  | (pack_bytes(a.z) << 8)  | (pack_bytes(a.w) << 12);
    ob |= (pack_bytes(b.x) << 16) | (pack_bytes(b.y) << 20) | (pack_bytes(b.z) << 24) | (pack_bytes(b.w) << 28);
  } else {
    const uint4* p = (const uint4*)((const unsigned*)mraw + (size_t)w * 32u);
#pragma unroll
    for (int k = 0; k < 8; ++k) {
      uint4 v = p[k];
      ob |= (v.x ? 1u : 0u) << (4 * k);
      ob |= (v.y ? 1u : 0u) << (4 * k + 1);
      ob |= (v.z ? 1u : 0u) << (4 * k + 2);
      ob |= (v.w ? 1u : 0u) << (4 * k + 3);
    }
  }
  bits[w] = ob;
}

// ---------------- K2: h = x@W; h_c16 (fp16 transposed), s_src/s_dst/s_dst_t ----------------
// 256 blocks x 256 thr; block = 16 rows, thread c = output column (head*64+d).
// x is read at block-uniform addresses -> compiler emits scalar loads
// (constant-cache broadcast), no LDS.
__global__ __launch_bounds__(256) void compute_h(const float* __restrict__ x,
                                                 const float* __restrict__ W,
                                                 const float* __restrict__ a_src,
                                                 const float* __restrict__ a_dst,
                                                 _Float16* __restrict__ h_c16,
                                                 float* __restrict__ s_src,
                                                 float* __restrict__ s_dst,
                                                 float* __restrict__ s_dst_t) {
  const int i0 = blockIdx.x * 16;
  const int c = threadIdx.x;

  float acc[16];
#pragma unroll
  for (int r = 0; r < 16; ++r) acc[r] = 0.f;

  for (int kk = 0; kk < IN_DIM / 4; ++kk) {
    const int k = kk * 4;
    float w0 = W[(size_t)(k + 0) * HD + c];
    float w1 = W[(size_t)(k + 1) * HD + c];
    float w2 = W[(size_t)(k + 2) * HD + c];
    float w3 = W[(size_t)(k + 3) * HD + c];
#pragma unroll
    for (int r = 0; r < 16; ++r) {
      float4 xv = *(const float4*)(x + (size_t)(i0 + r) * IN_DIM + k);  // uniform -> s_load
      acc[r] = fmaf(xv.x, w0, fmaf(xv.y, w1, fmaf(xv.z, w2, fmaf(xv.w, w3, acc[r]))));
    }
  }

  // fp16 transposed store: h_c16[c][i0..i0+15]
  f16x8 lo, hi;
#pragma unroll
  for (int r = 0; r < 8; ++r) { lo[r] = (_Float16)acc[r]; hi[r] = (_Float16)acc[r + 8]; }
  *(f16x8*)(h_c16 + (size_t)c * N + i0) = lo;
  *(f16x8*)(h_c16 + (size_t)c * N + i0 + 8) = hi;

  const int hw = c >> 6, lane = c & 63;
  const float as = a_src[lane], ad = a_dst[lane];
#pragma unroll
  for (int r = 0; r < 16; ++r) {
    float vs = acc[r] * as, vd = acc[r] * ad;
#pragma unroll
    for (int off = 1; off < 64; off <<= 1) {
      vs += __shfl_xor(vs, off);
      vd += __shfl_xor(vd, off);
    }
    if (lane == 0) {
      s_src[(size_t)(i0 + r) * HEADS + hw] = vs;
      s_dst[(size_t)(i0 + r) * HEADS + hw] = vd;
      s_dst_t[(size_t)hw * N + (i0 + r)] = vd;
    }
  }
}

// ---------------- K3: per-row softmax denom (single pass, no max-sub) ----------------
// 1024 blocks x 256 thr; wave = 1 row. Stores log2(l) and the masked-fill U:
// normal row: (log2 l, NEG_INF); empty row: (12 = log2 4096, 0) -> uniform 1/N.
__global__ __launch_bounds__(256) void gat_scores(const float* __restrict__ s_src,
                                                  const float* __restrict__ s_dst,
                                                  const unsigned* __restrict__ bits,
                                                  float* __restrict__ log2l_ws,
                                                  float* __restrict__ U_ws) {
  const int tid = threadIdx.x;
  const int wave = tid >> 6;
  const int lane = tid & 63;
  const int row = blockIdx.x * 4 + wave;

  const float4* sd4 = (const float4*)s_dst;
  const unsigned long long* mb64 = (const unsigned long long*)bits + (size_t)row * 64;

  float4 siv = ((const float4*)s_src)[row];
  float si[4] = {siv.x, siv.y, siv.z, siv.w};
  float l[4] = {0.f, 0.f, 0.f, 0.f};

  for (int jb = 0; jb < N / 64; ++jb) {
    float4 sjv = sd4[jb * 64 + lane];
    unsigned long long w = mb64[jb];
    bool e = (w >> lane) & 1ull;
#pragma unroll
    for (int h = 0; h < 4; ++h) {
      float v = lrelu(si[h] + f4get(sjv, h));
      l[h] += __expf(e ? v : NEG_INF);  // exp(-9e15) == 0
    }
  }
#pragma unroll
  for (int off = 1; off < 64; off <<= 1)
#pragma unroll
    for (int h = 0; h < 4; ++h) l[h] += __shfl_xor(l[h], off);

  if (lane == 0) {
#pragma unroll
    for (int h = 0; h < 4; ++h) {
      bool empty = (l[h] == 0.f);
      log2l_ws[(size_t)row * HEADS + h] = empty ? 12.0f : __log2f(l[h]);
      U_ws[(size_t)row * HEADS + h] = empty ? 0.f : NEG_INF;
    }
  }
}

// ---------------- K4: MFMA aggregation ----------------
// 1024 blocks x 256 thr. block = (itile = bid>>2 -> 16 rows) x (jq = bid&3 -> 1024 j).
// wave = head. A-frag (P) synthesized in registers: p = exp2(fma(x, log2e, -log2l)),
// x = e ? lrelu(si+sj) : U. Partial stores (atomic_mode=0) or atomicAdd fallback.
__global__ __launch_bounds__(256) void gat_aggr(const _Float16* __restrict__ h_c16,
                                                const float* __restrict__ s_src,
                                                const float* __restrict__ s_dst_t,
                                                const float* __restrict__ log2l_ws,
                                                const float* __restrict__ U_ws,
                                                const unsigned* __restrict__ bits,
                                                float* __restrict__ dst,
                                                int atomic_mode) {
  const int tid = threadIdx.x;
  const int head = tid >> 6;
  const int lane = tid & 63;
  const int m15 = lane & 15;
  const int quad = lane >> 4;
  const int itile = blockIdx.x >> 2;
  const int jq = blockIdx.x & 3;
  const int i0 = itile * 16;
  const int row = i0 + m15;

  const float si = s_src[(size_t)row * HEADS + head];
  const float nl2l = -log2l_ws[(size_t)row * HEADS + head];
  const float U = U_ws[(size_t)row * HEADS + head];

  const unsigned* mrow = bits + (size_t)row * 128 + jq * 32;           // 32 words = 1024 j
  const float* sjb = s_dst_t + (size_t)head * N + jq * 1024 + quad * 8;
  const _Float16* hrow = h_c16 + ((size_t)(head * 64 + m15)) * N + jq * 1024 + quad * 8;

  f32x4 acc0 = {0.f, 0.f, 0.f, 0.f}, acc1 = acc0, acc2 = acc0, acc3 = acc0;

  for (int g = 0; g < 8; ++g) {        // 8 groups x 4 chunks x 32 j
    uint4 mg = *(const uint4*)(mrow + g * 4);
    unsigned mw[4] = {mg.x, mg.y, mg.z, mg.w};
#pragma unroll
    for (int cc = 0; cc < 4; ++cc) {
      const int j0 = (g * 4 + cc) * 32;
      const unsigned w = mw[cc];
      const float4 sa = *(const float4*)(sjb + j0);
      const float4 sb = *(const float4*)(sjb + j0 + 4);
      const float sjs[8] = {sa.x, sa.y, sa.z, sa.w, sb.x, sb.y, sb.z, sb.w};

      f16x8 afrag;
#pragma unroll
      for (int t = 0; t < 8; ++t) {
        float v = lrelu(si + sjs[t]);
        float xx = ((w >> (quad * 8 + t)) & 1u) ? v : U;
        afrag[t] = (_Float16)__builtin_amdgcn_exp2f(fmaf(xx, LOG2E, nl2l));
      }

      const f16x8 b0 = *(const f16x8*)(hrow + j0);
      const f16x8 b1 = *(const f16x8*)(hrow + (size_t)16 * N + j0);
      const f16x8 b2 = *(const f16x8*)(hrow + (size_t)32 * N + j0);
      const f16x8 b3 = *(const f16x8*)(hrow + (size_t)48 * N + j0);

      acc0 = __builtin_amdgcn_mfma_f32_16x16x32_f16(afrag, b0, acc0, 0, 0, 0);
      acc1 = __builtin_amdgcn_mfma_f32_16x16x32_f16(afrag, b1, acc1, 0, 0, 0);
      acc2 = __builtin_amdgcn_mfma_f32_16x16x32_f16(afrag, b2, acc2, 0, 0, 0);
      acc3 = __builtin_amdgcn_mfma_f32_16x16x32_f16(afrag, b3, acc3, 0, 0, 0);
    }
  }

  // D layout: col = lane&15 (i'... no: col = d within tile), row = quad*4 + reg (i)
  if (atomic_mode) {
    float* obase = dst + (size_t)(i0 + quad * 4) * HD + head * 64 + m15;
#pragma unroll
    for (int reg = 0; reg < 4; ++reg) {
      atomicAdd(obase + (size_t)reg * HD + 0,  acc0[reg]);
      atomicAdd(obase + (size_t)reg * HD + 16, acc1[reg]);
      atomicAdd(obase + (size_t)reg * HD + 32, acc2[reg]);
      atomicAdd(obase + (size_t)reg * HD + 48, acc3[reg]);
    }
  } else {
    float* obase = dst + (size_t)jq * (N * HD) + (size_t)(i0 + quad * 4) * HD + head * 64 + m15;
#pragma unroll
    for (int reg = 0; reg < 4; ++reg) {
      obase[(size_t)reg * HD + 0]  = acc0[reg];
      obase[(size_t)reg * HD + 16] = acc1[reg];
      obase[(size_t)reg * HD + 32] = acc2[reg];
      obase[(size_t)reg * HD + 48] = acc3[reg];
    }
  }
}

// ---------------- K5: combine 4 partial slices ----------------
__global__ __launch_bounds__(256) void reduce_part(const float4* __restrict__ part,
                                                   float4* __restrict__ out) {
  const size_t idx = (size_t)blockIdx.x * 256 + threadIdx.x;  // 262144 float4s
  const size_t S = (size_t)N * HD / 4;
  float4 a = part[idx], b = part[idx + S], c = part[idx + 2 * S], d = part[idx + 3 * S];
  float4 o;
  o.x = (a.x + b.x) + (c.x + d.x);
  o.y = (a.y + b.y) + (c.y + d.y);
  o.z = (a.z + b.z) + (c.z + d.z);
  o.w = (a.w + b.w) + (c.w + d.w);
  out[idx] = o;
}

extern "C" void kernel_launch(void* const* d_in, const int* in_sizes, int n_in,
                              void* d_out, int out_size, void* d_ws, size_t ws_size,
                              hipStream_t stream) {
  (void)in_sizes; (void)n_in;
  const float* x = (const float*)d_in[0];
  const void* mask = d_in[1];
  const float* W = (const float*)d_in[2];
  const float* a_src = (const float*)d_in[3];
  const float* a_dst = (const float*)d_in[4];
  float* out = (float*)d_out;

  char* ws = (char*)d_ws;
  _Float16* h_c16 = (_Float16*)(ws + WS_HC_OFF);
  float* s_src = (float*)(ws + WS_SSRC_OFF);
  float* s_dst = (float*)(ws + WS_SDST_OFF);
  float* s_dst_t = (float*)(ws + WS_SDT_OFF);
  float* log2l_ws = (float*)(ws + WS_L2L_OFF);
  float* U_ws = (float*)(ws + WS_U_OFF);
  unsigned* bits = (unsigned*)(ws + WS_BITS_OFF);
  int* flag = (int*)(ws + WS_FLAG_OFF);
  float* partial = (float*)(ws + WS_PART_OFF);

  detect_fmt<<<1, 1024, 0, stream>>>((const unsigned*)mask, flag);
  pack_mask_k<<<(N * N / 32) / 256, 256, 0, stream>>>(mask, bits, flag);
  compute_h<<<N / 16, 256, 0, stream>>>(x, W, a_src, a_dst, h_c16, s_src, s_dst, s_dst_t);
  gat_scores<<<N / 4, 256, 0, stream>>>(s_src, s_dst, bits, log2l_ws, U_ws);

  if (ws_size >= (size_t)WS_NEEDED) {
    gat_aggr<<<(N / 16) * 4, 256, 0, stream>>>(h_c16, s_src, s_dst_t, log2l_ws, U_ws, bits,
                                               partial, 0);
    reduce_part<<<(N * HD / 4) / 256, 256, 0, stream>>>((const float4*)partial, (float4*)out);
  } else {
    hipMemsetAsync(out, 0, (size_t)out_size * sizeof(float), stream);
    gat_aggr<<<(N / 16) * 4, 256, 0, stream>>>(h_c16, s_src, s_dst_t, log2l_ws, U_ws, bits,
                                               out, 1);
  }
}

// Round 5
// 187.395 us; speedup vs baseline: 2.7225x; 1.2103x over previous
//
#include <hip/hip_runtime.h>
#include <math.h>

// DenseGATv2Layer: N=4096, IN=128, HEADS=4, OUT_DIM=64.
// R3: R2 post-mortem — aggr stalls ~5.7k cyc/chunk with all pipes idle; L2/L1
// path delivered only ~7.4 TB/s effective on 560MB of scattered h re-reads.
// Fixes: (1) M-tile 64 (512-thr blocks, 8 waves = 4 heads x 2 row-groups):
// h traffic /4, B-loads per MFMA /4; (2) XCD-aligned jsplit (jq = bid&7, XCD =
// bid%8 round-robin): each XCD L2 holds only its own 256KB h-slice; (3) VALU
// diet: log2e prescale, cvt_pkrtz packing; (4) jsplit=8 partials + reduce.
// R4: fix cvt_pkrtz return-type mismatch (__fp16 vec, not _Float16 vec).

#define N 4096
#define IN_DIM 128
#define HEADS 4
#define OUT_DIM 64
#define HD 256
#define NEG_INF -9.0e15f
#define LOG2E 1.4426950408889634f

typedef _Float16 f16x8 __attribute__((ext_vector_type(8)));
typedef __fp16 fp16x2 __attribute__((ext_vector_type(2)));
typedef float f32x4 __attribute__((ext_vector_type(4)));

union F16x8u { fp16x2 h2[4]; f16x8 v; };

// ws layout (bytes)
#define WS_HC_OFF    0u          // _Float16 h_c16[256][4096]   (2 MB)
#define WS_SSRC_OFF  2097152u    // float s_src[N][4]   (scaled by log2e)
#define WS_SDST_OFF  2162688u    // float s_dst[N][4]   (scaled)
#define WS_SDT_OFF   2228224u    // float s_dst_t[4][N] (scaled)
#define WS_L2L_OFF   2293760u    // float log2l[N][4]
#define WS_U_OFF     2359296u    // float U[N][4]
#define WS_BITS_OFF  2424832u    // uint bits[N][128]           (2 MB)
#define WS_FLAG_OFF  4521984u    // int flag
#define WS_PART_OFF  4718592u    // float partial[jsplit][N][256] (4MB each)
#define WS_SLICE     4194304u

__device__ __forceinline__ float f4get(float4 v, int h) {
  return h == 0 ? v.x : h == 1 ? v.y : h == 2 ? v.z : v.w;
}
__device__ __forceinline__ float lrelu(float v) { return fmaxf(v, 0.2f * v); }

// ---------------- K0: mask format detection ----------------
__global__ void detect_fmt(const unsigned* __restrict__ m, int* __restrict__ flag) {
  __shared__ int s_bad, s_gt1;
  if (threadIdx.x == 0) { s_bad = 0; s_gt1 = 0; }
  __syncthreads();
  int bad = 0, g = 0;
  for (int i = threadIdx.x; i < 4096; i += blockDim.x) {
    unsigned v = m[i];
    if (v & 0xFEFEFEFEu) bad = 1;
    if (v > 1u) g = 1;
  }
  if (bad) atomicOr(&s_bad, 1);
  if (g) atomicOr(&s_gt1, 1);
  __syncthreads();
  if (threadIdx.x == 0) *flag = (!s_bad && s_gt1) ? 1 : 0;  // 1 = byte elems
}

// ---------------- K1: pack mask to bits ----------------
__device__ __forceinline__ unsigned pack_bytes(unsigned v) {
  return (v & 1u) | ((v >> 7) & 2u) | ((v >> 14) & 4u) | ((v >> 21) & 8u);
}

__global__ __launch_bounds__(256) void pack_mask_k(const void* __restrict__ mraw,
                                                   unsigned* __restrict__ bits,
                                                   const int* __restrict__ flag) {
  int w = blockIdx.x * blockDim.x + threadIdx.x;
  unsigned ob = 0u;
  if (*flag) {
    const uint4* p = (const uint4*)((const unsigned char*)mraw + (size_t)w * 32u);
    uint4 a = p[0], b = p[1];
    ob  =  pack_bytes(a.x)        | (pack_bytes(a.y) << 4)  | (pack_bytes(a.z) << 8)  | (pack_bytes(a.w) << 12);
    ob |= (pack_bytes(b.x) << 16) | (pack_bytes(b.y) << 20) | (pack_bytes(b.z) << 24) | (pack_bytes(b.w) << 28);
  } else {
    const uint4* p = (const uint4*)((const unsigned*)mraw + (size_t)w * 32u);
#pragma unroll
    for (int k = 0; k < 8; ++k) {
      uint4 v = p[k];
      ob |= (v.x ? 1u : 0u) << (4 * k);
      ob |= (v.y ? 1u : 0u) << (4 * k + 1);
      ob |= (v.z ? 1u : 0u) << (4 * k + 2);
      ob |= (v.w ? 1u : 0u) << (4 * k + 3);
    }
  }
  bits[w] = ob;
}

// ---------------- K2: h = x@W; h_c16 fp16 transposed; scaled s vectors ----------------
// 512 blocks x 256 thr; block = 8 rows. x read at block-uniform addresses ->
// s_load broadcast. s_* stored PRESCALED by log2e (lrelu commutes with pos scale).
__global__ __launch_bounds__(256) void compute_h(const float* __restrict__ x,
                                                 const float* __restrict__ W,
                                                 const float* __restrict__ a_src,
                                                 const float* __restrict__ a_dst,
                                                 _Float16* __restrict__ h_c16,
                                                 float* __restrict__ s_src,
                                                 float* __restrict__ s_dst,
                                                 float* __restrict__ s_dst_t) {
  const int i0 = blockIdx.x * 8;
  const int c = threadIdx.x;

  float acc[8];
#pragma unroll
  for (int r = 0; r < 8; ++r) acc[r] = 0.f;

  for (int kk = 0; kk < IN_DIM / 4; ++kk) {
    const int k = kk * 4;
    float w0 = W[(size_t)(k + 0) * HD + c];
    float w1 = W[(size_t)(k + 1) * HD + c];
    float w2 = W[(size_t)(k + 2) * HD + c];
    float w3 = W[(size_t)(k + 3) * HD + c];
#pragma unroll
    for (int r = 0; r < 8; ++r) {
      float4 xv = *(const float4*)(x + (size_t)(i0 + r) * IN_DIM + k);  // uniform -> s_load
      acc[r] = fmaf(xv.x, w0, fmaf(xv.y, w1, fmaf(xv.z, w2, fmaf(xv.w, w3, acc[r]))));
    }
  }

  f16x8 lo;
#pragma unroll
  for (int r = 0; r < 8; ++r) lo[r] = (_Float16)acc[r];
  *(f16x8*)(h_c16 + (size_t)c * N + i0) = lo;

  const int hw = c >> 6, lane = c & 63;
  const float as = a_src[lane], ad = a_dst[lane];
#pragma unroll
  for (int r = 0; r < 8; ++r) {
    float vs = acc[r] * as, vd = acc[r] * ad;
#pragma unroll
    for (int off = 1; off < 64; off <<= 1) {
      vs += __shfl_xor(vs, off);
      vd += __shfl_xor(vd, off);
    }
    if (lane == 0) {
      s_src[(size_t)(i0 + r) * HEADS + hw] = vs * LOG2E;
      s_dst[(size_t)(i0 + r) * HEADS + hw] = vd * LOG2E;
      s_dst_t[(size_t)hw * N + (i0 + r)] = vd * LOG2E;
    }
  }
}

// ---------------- K3: per-row softmax denom (single pass, exp2 domain) ----------------
// 1024 blocks x 256 thr; wave = 1 row. Normal row: (log2 l, -1e38); empty row:
// (12, 0) -> exact uniform 1/4096.
__global__ __launch_bounds__(256) void gat_scores(const float* __restrict__ s_src,
                                                  const float* __restrict__ s_dst,
                                                  const unsigned* __restrict__ bits,
                                                  float* __restrict__ log2l_ws,
                                                  float* __restrict__ U_ws) {
  const int tid = threadIdx.x;
  const int wave = tid >> 6;
  const int lane = tid & 63;
  const int row = blockIdx.x * 4 + wave;

  const float4* sd4 = (const float4*)s_dst;
  const unsigned long long* mb64 = (const unsigned long long*)bits + (size_t)row * 64;

  float4 siv = ((const float4*)s_src)[row];
  float si[4] = {siv.x, siv.y, siv.z, siv.w};
  float l[4] = {0.f, 0.f, 0.f, 0.f};

  for (int jb = 0; jb < N / 256; ++jb) {
    float4 sj[4];
    unsigned long long w[4];
#pragma unroll
    for (int u = 0; u < 4; ++u) {
      sj[u] = sd4[jb * 256 + u * 64 + lane];
      w[u] = mb64[jb * 4 + u];
    }
#pragma unroll
    for (int u = 0; u < 4; ++u) {
      bool e = (w[u] >> lane) & 1ull;
#pragma unroll
      for (int h = 0; h < 4; ++h) {
        float ev = __builtin_amdgcn_exp2f(lrelu(si[h] + f4get(sj[u], h)));
        l[h] += e ? ev : 0.f;
      }
    }
  }
#pragma unroll
  for (int off = 1; off < 64; off <<= 1)
#pragma unroll
    for (int h = 0; h < 4; ++h) l[h] += __shfl_xor(l[h], off);

  if (lane == 0) {
#pragma unroll
    for (int h = 0; h < 4; ++h) {
      bool empty = (l[h] == 0.f);
      log2l_ws[(size_t)row * HEADS + h] = empty ? 12.0f : __log2f(l[h]);
      U_ws[(size_t)row * HEADS + h] = empty ? 0.f : -1.0e38f;
    }
  }
}

// ---------------- K4: MFMA aggregation, M=64, XCD-aligned jsplit ----------------
// grid = 64 * jsplit blocks x 512 thr (8 waves). jq = bid & (jsplit-1): with
// round-robin XCD dispatch and jsplit=8, each XCD sees exactly one jq ->
// its L2 only holds the 256KB h-slice + partial slice for that jq.
// wave: head = w&3, row-group mg = w>>2 (2 Mtiles of 16). Per 32-j chunk:
// 2 A-frags synthesized in regs, 4 B-frags, 8 MFMAs.
__global__ __launch_bounds__(512, 4) void gat_aggr(const _Float16* __restrict__ h_c16,
                                                   const float* __restrict__ s_src,
                                                   const float* __restrict__ s_dst_t,
                                                   const float* __restrict__ log2l_ws,
                                                   const float* __restrict__ U_ws,
                                                   const unsigned* __restrict__ bits,
                                                   float* __restrict__ dst,
                                                   int jshift, int atomic_mode) {
  const int jsplit = 1 << jshift;
  const int jrange = N >> jshift;          // 512 for jsplit=8
  const int chunks = jrange >> 5;          // 16
  const int tid = threadIdx.x;
  const int wave = tid >> 6;
  const int lane = tid & 63;
  const int head = wave & 3;
  const int mg = wave >> 2;
  const int m15 = lane & 15;
  const int quad = lane >> 4;
  const int jq = blockIdx.x & (jsplit - 1);
  const int itile = blockIdx.x >> jshift;
  const int i0 = itile * 64;
  const int rA = i0 + mg * 32 + m15;
  const int rB = rA + 16;

  const float siA = s_src[(size_t)rA * HEADS + head];
  const float siB = s_src[(size_t)rB * HEADS + head];
  const float nlA = -log2l_ws[(size_t)rA * HEADS + head];
  const float nlB = -log2l_ws[(size_t)rB * HEADS + head];
  const float UA = U_ws[(size_t)rA * HEADS + head];
  const float UB = U_ws[(size_t)rB * HEADS + head];

  const unsigned* maskA = bits + (size_t)rA * 128 + (size_t)jq * chunks;
  const unsigned* maskB = bits + (size_t)rB * 128 + (size_t)jq * chunks;
  const float* sjb = s_dst_t + (size_t)head * N + (size_t)jq * jrange + quad * 8;
  const _Float16* hbase = h_c16 + ((size_t)(head * 64 + m15)) * N + (size_t)jq * jrange + quad * 8;

  f32x4 accA0 = {0.f, 0.f, 0.f, 0.f}, accA1 = accA0, accA2 = accA0, accA3 = accA0;
  f32x4 accB0 = accA0, accB1 = accA0, accB2 = accA0, accB3 = accA0;

  const int shq = quad * 8;

  for (int g = 0; g < chunks / 4; ++g) {
    uint4 mA4 = *(const uint4*)(maskA + g * 4);
    uint4 mB4 = *(const uint4*)(maskB + g * 4);
    unsigned mAa[4] = {mA4.x, mA4.y, mA4.z, mA4.w};
    unsigned mBa[4] = {mB4.x, mB4.y, mB4.z, mB4.w};
#pragma unroll
    for (int cc = 0; cc < 4; ++cc) {
      const int j0 = (g * 4 + cc) * 32;
      const unsigned wA = mAa[cc] >> shq;
      const unsigned wB = mBa[cc] >> shq;
      const float4 sa = *(const float4*)(sjb + j0);
      const float4 sb = *(const float4*)(sjb + j0 + 4);
      const float sjs[8] = {sa.x, sa.y, sa.z, sa.w, sb.x, sb.y, sb.z, sb.w};

      const f16x8 b0 = *(const f16x8*)(hbase + j0);
      const f16x8 b1 = *(const f16x8*)(hbase + (size_t)16 * N + j0);
      const f16x8 b2 = *(const f16x8*)(hbase + (size_t)32 * N + j0);
      const f16x8 b3 = *(const f16x8*)(hbase + (size_t)48 * N + j0);

      F16x8u uA, uB;
#pragma unroll
      for (int t2 = 0; t2 < 4; ++t2) {
        float pA[2], pB[2];
#pragma unroll
        for (int q = 0; q < 2; ++q) {
          const int t = t2 * 2 + q;
          const float sj = sjs[t];
          float vA = lrelu(siA + sj);
          float vB = lrelu(siB + sj);
          float xA = ((wA >> t) & 1u) ? vA : UA;
          float xB = ((wB >> t) & 1u) ? vB : UB;
          pA[q] = __builtin_amdgcn_exp2f(xA + nlA);
          pB[q] = __builtin_amdgcn_exp2f(xB + nlB);
        }
        uA.h2[t2] = __builtin_amdgcn_cvt_pkrtz(pA[0], pA[1]);
        uB.h2[t2] = __builtin_amdgcn_cvt_pkrtz(pB[0], pB[1]);
      }

      accA0 = __builtin_amdgcn_mfma_f32_16x16x32_f16(uA.v, b0, accA0, 0, 0, 0);
      accA1 = __builtin_amdgcn_mfma_f32_16x16x32_f16(uA.v, b1, accA1, 0, 0, 0);
      accA2 = __builtin_amdgcn_mfma_f32_16x16x32_f16(uA.v, b2, accA2, 0, 0, 0);
      accA3 = __builtin_amdgcn_mfma_f32_16x16x32_f16(uA.v, b3, accA3, 0, 0, 0);
      accB0 = __builtin_amdgcn_mfma_f32_16x16x32_f16(uB.v, b0, accB0, 0, 0, 0);
      accB1 = __builtin_amdgcn_mfma_f32_16x16x32_f16(uB.v, b1, accB1, 0, 0, 0);
      accB2 = __builtin_amdgcn_mfma_f32_16x16x32_f16(uB.v, b2, accB2, 0, 0, 0);
      accB3 = __builtin_amdgcn_mfma_f32_16x16x32_f16(uB.v, b3, accB3, 0, 0, 0);
    }
  }

  // D layout: col = lane&15 (d in tile), row = quad*4 + reg.
  const int colb = head * 64 + m15;
  if (atomic_mode) {
    float* oA = dst + (size_t)(i0 + mg * 32 + quad * 4) * HD + colb;
    float* oB = oA + (size_t)16 * HD;
#pragma unroll
    for (int reg = 0; reg < 4; ++reg) {
      atomicAdd(oA + (size_t)reg * HD + 0,  accA0[reg]);
      atomicAdd(oA + (size_t)reg * HD + 16, accA1[reg]);
      atomicAdd(oA + (size_t)reg * HD + 32, accA2[reg]);
      atomicAdd(oA + (size_t)reg * HD + 48, accA3[reg]);
      atomicAdd(oB + (size_t)reg * HD + 0,  accB0[reg]);
      atomicAdd(oB + (size_t)reg * HD + 16, accB1[reg]);
      atomicAdd(oB + (size_t)reg * HD + 32, accB2[reg]);
      atomicAdd(oB + (size_t)reg * HD + 48, accB3[reg]);
    }
  } else {
    float* oA = dst + (size_t)jq * (N * HD) + (size_t)(i0 + mg * 32 + quad * 4) * HD + colb;
    float* oB = oA + (size_t)16 * HD;
#pragma unroll
    for (int reg = 0; reg < 4; ++reg) {
      oA[(size_t)reg * HD + 0]  = accA0[reg];
      oA[(size_t)reg * HD + 16] = accA1[reg];
      oA[(size_t)reg * HD + 32] = accA2[reg];
      oA[(size_t)reg * HD + 48] = accA3[reg];
      oB[(size_t)reg * HD + 0]  = accB0[reg];
      oB[(size_t)reg * HD + 16] = accB1[reg];
      oB[(size_t)reg * HD + 32] = accB2[reg];
      oB[(size_t)reg * HD + 48] = accB3[reg];
    }
  }
}

// ---------------- K5: combine jsplit partial slices ----------------
__global__ __launch_bounds__(256) void reduce_part(const float4* __restrict__ part,
                                                   float4* __restrict__ out, int jsplit) {
  const size_t idx = (size_t)blockIdx.x * 256 + threadIdx.x;
  const size_t S = (size_t)N * HD / 4;
  float4 o = part[idx];
  for (int k = 1; k < jsplit; ++k) {
    float4 a = part[idx + (size_t)k * S];
    o.x += a.x; o.y += a.y; o.z += a.z; o.w += a.w;
  }
  out[idx] = o;
}

extern "C" void kernel_launch(void* const* d_in, const int* in_sizes, int n_in,
                              void* d_out, int out_size, void* d_ws, size_t ws_size,
                              hipStream_t stream) {
  (void)in_sizes; (void)n_in;
  const float* x = (const float*)d_in[0];
  const void* mask = d_in[1];
  const float* W = (const float*)d_in[2];
  const float* a_src = (const float*)d_in[3];
  const float* a_dst = (const float*)d_in[4];
  float* out = (float*)d_out;

  char* ws = (char*)d_ws;
  _Float16* h_c16 = (_Float16*)(ws + WS_HC_OFF);
  float* s_src = (float*)(ws + WS_SSRC_OFF);
  float* s_dst = (float*)(ws + WS_SDST_OFF);
  float* s_dst_t = (float*)(ws + WS_SDT_OFF);
  float* log2l_ws = (float*)(ws + WS_L2L_OFF);
  float* U_ws = (float*)(ws + WS_U_OFF);
  unsigned* bits = (unsigned*)(ws + WS_BITS_OFF);
  int* flag = (int*)(ws + WS_FLAG_OFF);
  float* partial = (float*)(ws + WS_PART_OFF);

  detect_fmt<<<1, 1024, 0, stream>>>((const unsigned*)mask, flag);
  pack_mask_k<<<(N * N / 32) / 256, 256, 0, stream>>>(mask, bits, flag);
  compute_h<<<N / 8, 256, 0, stream>>>(x, W, a_src, a_dst, h_c16, s_src, s_dst, s_dst_t);
  gat_scores<<<N / 4, 256, 0, stream>>>(s_src, s_dst, bits, log2l_ws, U_ws);

  int jshift;
  if (ws_size >= (size_t)WS_PART_OFF + 8u * WS_SLICE) jshift = 3;
  else if (ws_size >= (size_t)WS_PART_OFF + 4u * WS_SLICE) jshift = 2;
  else jshift = -1;

  if (jshift >= 0) {
    const int jsplit = 1 << jshift;
    gat_aggr<<<(N / 64) * jsplit, 512, 0, stream>>>(h_c16, s_src, s_dst_t, log2l_ws, U_ws,
                                                    bits, partial, jshift, 0);
    reduce_part<<<(N * HD / 4) / 256, 256, 0, stream>>>((const float4*)partial, (float4*)out,
                                                        jsplit);
  } else {
    (void)hipMemsetAsync(out, 0, (size_t)out_size * sizeof(float), stream);
    gat_aggr<<<(N / 64) * 8, 512, 0, stream>>>(h_c16, s_src, s_dst_t, log2l_ws, U_ws,
                                               bits, out, 3, 1);
  }
}